// Round 8
// baseline (320.585 us; speedup 1.0000x reference)
//
#include <hip/hip_runtime.h>
#include <hip/hip_bf16.h>
#include <cstddef>

#define NB 2048
#define TENC 168
#define TPRED 24

typedef _Float16 h8 __attribute__((ext_vector_type(8)));
typedef float f4v __attribute__((ext_vector_type(4)));

#define MFMA16(a, b, c) __builtin_amdgcn_mfma_f32_16x16x32_f16((a), (b), (c), 0, 0, 0)

// LDS-only barrier: waits DS ops, does NOT drain vmcnt (global loads/stores
// stay in flight across it).
#define LBAR() asm volatile("s_waitcnt lgkmcnt(0)\ns_barrier" ::: "memory")

__device__ __forceinline__ float gate_fast(float a, float g) {
  a = fminf(a, 15.0f);
  const float e2a = __builtin_amdgcn_exp2f(a * 2.88539008177793f);    // e^(2a)
  const float eg  = __builtin_amdgcn_exp2f(g * -1.44269504088896f);   // e^(-g)
  return (e2a - 1.0f) * __builtin_amdgcn_rcpf((e2a + 1.0f) * (1.0f + eg));
}
__device__ __forceinline__ float tanh_fast(float u) {
  const float e2 = __builtin_amdgcn_exp2f(fminf(u, 15.0f) * 2.88539008177793f);
  return (e2 - 1.0f) * __builtin_amdgcn_rcpf(e2 + 1.0f);
}
__device__ __forceinline__ h8 cvt8(const f4v a, const f4v b) {
  h8 r;
  #pragma unroll
  for (int u = 0; u < 4; ++u) { r[u] = (_Float16)a[u]; r[u + 4] = (_Float16)b[u]; }
  return r;
}

// ---------------------------------------------------------------------------
// Phase 1 (round 8): 2-stream, 1-barrier-per-layer recurrent decoder.
// 64 blocks x 512 threads; block owns 32 elements = 2 streams of 16.
// Both streams share every phase (barrier fixed cost amortized 2x).
// Producers (waves 0-3), per phase l, per stream:
//   S = state_l@W2 + b2 (prefetched state frags, starts immediately)
//   Z += gated_{l-1}@W43   (l=0: Z = x@W3)
//   dc = Z + S -> gate -> g16v[s][l&1]; prefetch state(l+1).
// Consumers (waves 4-7), per phase l>=1, per stream (LAGGED lp = l-1):
//   osk/ore = gated_lp @ W4 + b4; skip -> skl (LDS, coalesced flush at T);
//   x += res -> ring slot(lp,t). T: lp=5 skip, flush skl->skbuf (dwordx4).
// Barriers: 7 LBARs per step for 32 elements (vs r6: 12-13 per 16 elements).
// k-mapping k = kk*32 + q*8 + j consistent across all A/B frags (verified).
// ---------------------------------------------------------------------------
__global__ __launch_bounds__(512, 1) void dec_phase1(
    const float* __restrict__ feat,    // [2048][24][15]
    const float* __restrict__ dinit,   // [2048][1]
    const float* __restrict__ enc,     // [6][2048][168][64]
    const float* __restrict__ W1,      // [16][64]
    const float* __restrict__ b1,      // [64]
    const float* __restrict__ W2,      // [64][128]
    const float* __restrict__ b2,      // [128]
    const float* __restrict__ W3,      // [64][128]
    const float* __restrict__ W4,      // [64][128]
    const float* __restrict__ b4,      // [128]
    _Float16* __restrict__ skbuf,      // [2048*24][384] f16
    int t_steps)                       // runtime 24: blocks t-loop unroll
{
  __shared__ _Float16 ring[2][23][16][72];  // 103.5 KB dilation rings
  __shared__ _Float16 g16v[2][2][16][72];   //   9.0 KB gated [stream][layer-parity]
  __shared__ _Float16 xf16[2][16][72];      //   4.5 KB embed x(t)
  __shared__ float    xf32[2][64][20];      //  10.0 KB embed x(t) [col][el]
  __shared__ _Float16 skl[2][16][392];      //  24.5 KB skip staging (W43h alias)

  const int tid = threadIdx.x;
  const int w   = tid >> 6;
  const int ln  = tid & 63;
  const int i   = ln & 15;
  const int q   = ln >> 4;
  const int q8  = q * 8;
  const int e0  = blockIdx.x * 32;

  // -------- prologue 1: stage W3 / W4res (f32) in ring region --------
  float* W3s  = (float*)&ring[0][0][0][0];   // [64][128] 32 KB
  float* W4rs = W3s + 64 * 128;              // [64][64]  16 KB
  for (int idx = tid; idx < 2048; idx += 512)
    ((float4*)W3s)[idx] = ((const float4*)W3)[idx];
  for (int idx = tid; idx < 1024; idx += 512) {
    const int row = idx >> 4, seg = idx & 15;
    *(float4*)&W4rs[row * 64 + seg * 4] = *(const float4*)&W4[row * 128 + 64 + seg * 4];
  }
  __syncthreads();

  // -------- prologue 2: W43 = W4res @ W3 (f16), parked in skl region --------
  _Float16* W43h = &skl[0][0][0];            // [64][136] = 17.4 KB <= 24.5
  {
    const int c = tid & 127, k0 = (tid >> 7) << 4;
    float acc[16];
    #pragma unroll
    for (int r = 0; r < 16; ++r) acc[r] = 0.0f;
    for (int m = 0; m < 64; ++m) {
      const float w3v = W3s[m * 128 + c];
      #pragma unroll
      for (int r = 0; r < 16; ++r) acc[r] += W4rs[(k0 + r) * 64 + m] * w3v;
    }
    #pragma unroll
    for (int r = 0; r < 16; ++r) W43h[(k0 + r) * 136 + c] = (_Float16)acc[r];
  }
  __syncthreads();

  // -------- prologue 3: weight fragments --------
  const int cf = (w < 4) ? (16 * w + i) : (16 * (w - 4) + i);
  const int cg = 64 + cf;
  const int cw = w - 4;                      // consumer wave id (w>=4)

  h8 BW2f[2], BW2g[2], BW3f[2], BW3g[2], B43f[2], B43g[2];  // producer
  h8 B4s[2], B4r[2];                                        // consumer
  float b2f = 0.f, b2g = 0.f, b4s_ = 0.f, b4r_ = 0.f;
  if (w < 4) {
    #pragma unroll
    for (int kk = 0; kk < 2; ++kk)
      #pragma unroll
      for (int j = 0; j < 8; ++j) {
        const int k = kk * 32 + q8 + j;
        BW2f[kk][j] = (_Float16)W2[k * 128 + cf];
        BW2g[kk][j] = (_Float16)W2[k * 128 + cg];
        BW3f[kk][j] = (_Float16)W3[k * 128 + cf];
        BW3g[kk][j] = (_Float16)W3[k * 128 + cg];
        B43f[kk][j] = W43h[k * 136 + cf];
        B43g[kk][j] = W43h[k * 136 + cg];
      }
    b2f = b2[cf]; b2g = b2[cg];
  } else {
    #pragma unroll
    for (int kk = 0; kk < 2; ++kk)
      #pragma unroll
      for (int j = 0; j < 8; ++j) {
        const int k = kk * 32 + q8 + j;
        B4s[kk][j] = (_Float16)W4[k * 128 + cf];        // skip cols 0..63
        B4r[kk][j] = (_Float16)W4[k * 128 + 64 + cf];   // res  cols 64..127
      }
    b4s_ = b4[cf]; b4r_ = b4[64 + cf];
  }
  // embed weights (all waves; each embeds 4 elements)
  float w1r[16];
  #pragma unroll
  for (int ii = 0; ii < 16; ++ii) w1r[ii] = W1[ii * 64 + ln];
  const float b1r = b1[ln];
  float ini4[4];
  #pragma unroll
  for (int s2 = 0; s2 < 4; ++s2) ini4[s2] = dinit[e0 + 4 * w + s2];

  // -------- ring preload (enc tails l<=3), both streams --------
  for (int idx = tid; idx < 3840; idx += 512) {
    const int str = (idx >= 1920) ? 1 : 0;
    const int rr  = idx - 1920 * str;
    const int c = rr & 7, el = (rr >> 3) & 15, sl = rr >> 7;  // sl = 0..14
    int l, j;
    if (sl == 0)      { l = 0; j = 0; }
    else if (sl < 3)  { l = 1; j = sl - 1; }
    else if (sl < 7)  { l = 2; j = sl - 3; }
    else              { l = 3; j = sl - 7; }
    const int d = 1 << l;
    const float* ep = enc + (((size_t)l * NB + e0 + 16 * str + el) * TENC + (TENC + j - d)) * 64 + c * 8;
    h8 hv;
    #pragma unroll
    for (int u = 0; u < 8; ++u) hv[u] = (_Float16)ep[u];
    *(h8*)&ring[str][sl][el][c * 8] = hv;
  }

  // -------- embed t=0 (4 elements per wave) --------
  #pragma unroll
  for (int s2 = 0; s2 < 4; ++s2) {
    const int eg = 4 * w + s2, str = eg >> 4, el = eg & 15;
    const float* fp = feat + (size_t)(e0 + eg) * TPRED * 15;
    float u = b1r + ini4[s2] * w1r[0];
    #pragma unroll
    for (int ii = 0; ii < 15; ++ii) u += fp[ii] * w1r[ii + 1];
    const float xv = tanh_fast(u);
    xf16[str][el][ln] = (_Float16)xv;
    xf32[str][ln][el] = xv;
  }
  __syncthreads();   // last full barrier

  // -------- producer persistent state frags: state(l=0, t=0) --------
  h8 stA[2], stB[2];
  if (w < 4) {
    #pragma unroll
    for (int s = 0; s < 2; ++s) {
      stA[s] = *(const h8*)&ring[s][0][i][q8];
      stB[s] = *(const h8*)&ring[s][0][i][32 + q8];
    }
  }
  f4v Zf[2], Zg[2];

  for (int t = 0; t < t_steps; ++t) {
    f4v pa4[2][4], pa5[2][4];                 // enc f32 (live L0..L2)
    h8 s4A[2], s4B[2], s5A[2], s5B[2];        // enc f16 frags (from L2)
    f4v ff0[4], ff1[4], ff2[4];               // feat prefetch (live L3..T)
    float2 ffd[4]; float ffe[4];
    f4v xreg[2];                              // consumer running x

    #pragma unroll
    for (int l = 0; l < 6; ++l) {
      if (w < 4) {
        // ======== PRODUCER ========
        if (l == 0) {
          // enc slice loads for l=4 (t<16) and l=5, both streams
          #pragma unroll
          for (int s = 0; s < 2; ++s) {
            if (t < 16) {
              const float* e4 = enc + (((size_t)4 * NB + e0 + 16 * s + i) * TENC + (152 + t)) * 64 + q8;
              pa4[s][0] = *(const f4v*)(e4);      pa4[s][1] = *(const f4v*)(e4 + 4);
              pa4[s][2] = *(const f4v*)(e4 + 32); pa4[s][3] = *(const f4v*)(e4 + 36);
            }
            const float* e5 = enc + (((size_t)5 * NB + e0 + 16 * s + i) * TENC + (136 + t)) * 64 + q8;
            pa5[s][0] = *(const f4v*)(e5);      pa5[s][1] = *(const f4v*)(e5 + 4);
            pa5[s][2] = *(const f4v*)(e5 + 32); pa5[s][3] = *(const f4v*)(e5 + 36);
          }
        }
        if (l == 2) {
          #pragma unroll
          for (int s = 0; s < 2; ++s) {
            s4A[s] = cvt8(pa4[s][0], pa4[s][1]); s4B[s] = cvt8(pa4[s][2], pa4[s][3]);
            s5A[s] = cvt8(pa5[s][0], pa5[s][1]); s5B[s] = cvt8(pa5[s][2], pa5[s][3]);
          }
        }
        // prefetch state(l+1, t) — issued early, consumed next phase
        h8 ntA[2], ntB[2];
        if (l < 5) {
          #pragma unroll
          for (int s = 0; s < 2; ++s) {
            if (l + 1 <= 3) {
              const int d2 = 1 << (l + 1);
              const int slot = (d2 - 1) + (t & (d2 - 1));
              ntA[s] = *(const h8*)&ring[s][slot][i][q8];
              ntB[s] = *(const h8*)&ring[s][slot][i][32 + q8];
            } else if (l + 1 == 4) {
              if (t < 16) { ntA[s] = s4A[s]; ntB[s] = s4B[s]; }
              else {
                const int slot = 15 + (t & 7);
                ntA[s] = *(const h8*)&ring[s][slot][i][q8];
                ntB[s] = *(const h8*)&ring[s][slot][i][32 + q8];
              }
            } else { ntA[s] = s5A[s]; ntB[s] = s5B[s]; }
          }
        }
        // recurrence: S (independent) || Z (chain) -> dc -> gate
        #pragma unroll
        for (int s = 0; s < 2; ++s) {
          f4v Sf = {b2f, b2f, b2f, b2f}, Sg = {b2g, b2g, b2g, b2g};
          Sf = MFMA16(stA[s], BW2f[0], Sf); Sf = MFMA16(stB[s], BW2f[1], Sf);
          Sg = MFMA16(stA[s], BW2g[0], Sg); Sg = MFMA16(stB[s], BW2g[1], Sg);
          if (l == 0) {
            const h8 a2 = *(const h8*)&xf16[s][i][q8];
            const h8 a3 = *(const h8*)&xf16[s][i][32 + q8];
            f4v z0 = {0, 0, 0, 0};
            Zf[s] = MFMA16(a2, BW3f[0], z0); Zf[s] = MFMA16(a3, BW3f[1], Zf[s]);
            Zg[s] = MFMA16(a2, BW3g[0], z0); Zg[s] = MFMA16(a3, BW3g[1], Zg[s]);
          } else {
            const h8 g0 = *(const h8*)&g16v[s][(l - 1) & 1][i][q8];
            const h8 g1 = *(const h8*)&g16v[s][(l - 1) & 1][i][32 + q8];
            Zf[s] = MFMA16(g0, B43f[0], Zf[s]); Zf[s] = MFMA16(g1, B43f[1], Zf[s]);
            Zg[s] = MFMA16(g0, B43g[0], Zg[s]); Zg[s] = MFMA16(g1, B43g[1], Zg[s]);
          }
          const f4v dcf = Zf[s] + Sf;
          const f4v dcg = Zg[s] + Sg;
          #pragma unroll
          for (int r = 0; r < 4; ++r)
            g16v[s][l & 1][4 * q + r][cf] = (_Float16)gate_fast(dcf[r], dcg[r]);
        }
        if (l < 5) {
          #pragma unroll
          for (int s = 0; s < 2; ++s) { stA[s] = ntA[s]; stB[s] = ntB[s]; }
        }
      } else {
        // ======== CONSUMER (lagged lp = l-1) ========
        if (l == 0) {
          #pragma unroll
          for (int s = 0; s < 2; ++s)
            xreg[s] = *(const f4v*)&xf32[s][cf][4 * q];
        } else {
          const int lp = l - 1, dlp = 1 << lp;
          const int slot = (lp <= 3) ? (dlp - 1) + (t & (dlp - 1)) : 15 + (t & 7);
          const bool wr = (lp <= 3) || (t <= 7);
          #pragma unroll
          for (int s = 0; s < 2; ++s) {
            const h8 g0 = *(const h8*)&g16v[s][(l - 1) & 1][i][q8];
            const h8 g1 = *(const h8*)&g16v[s][(l - 1) & 1][i][32 + q8];
            f4v osk = {b4s_, b4s_, b4s_, b4s_};
            osk = MFMA16(g0, B4s[0], osk); osk = MFMA16(g1, B4s[1], osk);
            f4v ore = {b4r_, b4r_, b4r_, b4r_};
            ore = MFMA16(g0, B4r[0], ore); ore = MFMA16(g1, B4r[1], ore);
            #pragma unroll
            for (int r = 0; r < 4; ++r) {
              skl[s][4 * q + r][lp * 64 + cf] = (_Float16)fmaxf(osk[r], 0.0f);
              xreg[s][r] += ore[r];
              if (wr) ring[s][slot][4 * q + r][cf] = (_Float16)xreg[s][r];
            }
          }
        }
      }
      // feat prefetch for t+1 (all waves, 4 elements each)
      if (l == 3 && t + 1 < t_steps) {
        #pragma unroll
        for (int s2 = 0; s2 < 4; ++s2) {
          const float* fp = feat + ((size_t)(e0 + 4 * w + s2) * TPRED + (t + 1)) * 15;
          ff0[s2] = *(const f4v*)(fp);
          ff1[s2] = *(const f4v*)(fp + 4);
          ff2[s2] = *(const f4v*)(fp + 8);
          ffd[s2] = *(const float2*)(fp + 12);
          ffe[s2] = fp[14];
        }
      }
      LBAR();
    }

    // ======== T phase ========
    if (w < 4) {
      // prefetch state(0, t+1) = x_1(t), written by consumers at phase L1
      #pragma unroll
      for (int s = 0; s < 2; ++s) {
        stA[s] = *(const h8*)&ring[s][0][i][q8];
        stB[s] = *(const h8*)&ring[s][0][i][32 + q8];
      }
    } else {
      // lagged lp=5 skip
      #pragma unroll
      for (int s = 0; s < 2; ++s) {
        const h8 g0 = *(const h8*)&g16v[s][1][i][q8];
        const h8 g1 = *(const h8*)&g16v[s][1][i][32 + q8];
        f4v osk = {b4s_, b4s_, b4s_, b4s_};
        osk = MFMA16(g0, B4s[0], osk); osk = MFMA16(g1, B4s[1], osk);
        #pragma unroll
        for (int r = 0; r < 4; ++r)
          skl[s][4 * q + r][5 * 64 + cf] = (_Float16)fmaxf(osk[r], 0.0f);
      }
      asm volatile("s_waitcnt lgkmcnt(0)" ::: "memory");
      // flush own-strip skips: 6 dwordx4 per lane, 32B-coalesced
      #pragma unroll
      for (int s = 0; s < 2; ++s)
        #pragma unroll
        for (int it = 0; it < 3; ++it) {
          const int k2 = ln + 64 * it;          // 0..191
          const int el = k2 / 12, rest = k2 - el * 12;
          const int lp = rest >> 1, hf = rest & 1;
          const int col = lp * 64 + 16 * cw + 8 * hf;
          const h8 v = *(const h8*)&skl[s][el][col];
          *(h8*)&skbuf[((size_t)(e0 + 16 * s + el) * TPRED + t) * 384 + col] = v;
        }
    }
    // embed for t+1 (all waves)
    if (t + 1 < t_steps) {
      #pragma unroll
      for (int s2 = 0; s2 < 4; ++s2) {
        const int eg = 4 * w + s2, str = eg >> 4, el = eg & 15;
        float u = b1r + ini4[s2] * w1r[0];
        u += ff0[s2][0] * w1r[1]  + ff0[s2][1] * w1r[2]  + ff0[s2][2] * w1r[3]  + ff0[s2][3] * w1r[4];
        u += ff1[s2][0] * w1r[5]  + ff1[s2][1] * w1r[6]  + ff1[s2][2] * w1r[7]  + ff1[s2][3] * w1r[8];
        u += ff2[s2][0] * w1r[9]  + ff2[s2][1] * w1r[10] + ff2[s2][2] * w1r[11] + ff2[s2][3] * w1r[12];
        u += ffd[s2].x  * w1r[13] + ffd[s2].y  * w1r[14] + ffe[s2]   * w1r[15];
        const float xv = tanh_fast(u);
        xf16[str][el][ln] = (_Float16)xv;
        xf32[str][ln][el] = xv;
      }
    }
    LBAR();
  }
}

// ---------------------------------------------------------------------------
// Phase 2: y = relu( sk @ W5 + b5 ) @ W6 + b6, 49152 rows, f16 MFMA.
// 512 blocks x 96 rows; 76.5 KB LDS -> 2 blocks/CU.
// ---------------------------------------------------------------------------
__global__ __launch_bounds__(512, 1) void dec_phase2(
    const _Float16* __restrict__ skbuf,  // [49152][384] f16 (already relu'd)
    const float* __restrict__ W5,        // [384][128]
    const float* __restrict__ b5,        // [128]
    const float* __restrict__ W6,        // [128]
    const float* __restrict__ b6,        // [1]
    float* __restrict__ out)             // [49152]
{
  __shared__ _Float16 As[96][392];       // 73.5 KB
  __shared__ float red[96][8];           // 3 KB

  const int tid = threadIdx.x;
  const int w   = tid >> 6;
  const int ln  = tid & 63;
  const int i   = ln & 15;
  const int q   = ln >> 4;
  const int R0  = blockIdx.x * 96;
  const int col = 16 * w + i;

  h8 B5[12];
  #pragma unroll
  for (int kk = 0; kk < 12; ++kk)
    #pragma unroll
    for (int j = 0; j < 8; ++j)
      B5[kk][j] = (_Float16)W5[(size_t)(kk * 32 + q * 8 + j) * 128 + col];
  const float b5r = b5[col], w6r = W6[col];

  #pragma unroll
  for (int it = 0; it < 9; ++it) {
    const int idx = tid + it * 512;            // 0..4607 = 96 rows x 48 segs
    const h8 v = *(const h8*)&skbuf[(size_t)(R0 + idx / 48) * 384 + (idx % 48) * 8];
    *(h8*)&As[idx / 48][(idx % 48) * 8] = v;
  }
  __syncthreads();

  #pragma unroll
  for (int m = 0; m < 6; ++m) {
    f4v acc = {0, 0, 0, 0};
    #pragma unroll
    for (int kk = 0; kk < 12; ++kk) {
      const h8 a = *(const h8*)&As[16 * m + i][kk * 32 + q * 8];
      acc = MFMA16(a, B5[kk], acc);
    }
    float py[4];
    #pragma unroll
    for (int r = 0; r < 4; ++r)
      py[r] = fmaxf(acc[r] + b5r, 0.0f) * w6r;
    #pragma unroll
    for (int r = 0; r < 4; ++r) {
      float v = py[r];
      v += __shfl_xor(v, 1);
      v += __shfl_xor(v, 2);
      v += __shfl_xor(v, 4);
      v += __shfl_xor(v, 8);
      py[r] = v;
    }
    if (i == 0) {
      #pragma unroll
      for (int r = 0; r < 4; ++r) red[16 * m + 4 * q + r][w] = py[r];
    }
  }
  __syncthreads();

  if (tid < 96) {
    const f4v r0 = *(const f4v*)&red[tid][0];
    const f4v r1 = *(const f4v*)&red[tid][4];
    out[R0 + tid] = b6[0] + r0[0] + r0[1] + r0[2] + r0[3]
                          + r1[0] + r1[1] + r1[2] + r1[3];
  }
}

extern "C" void kernel_launch(void* const* d_in, const int* in_sizes, int n_in,
                              void* d_out, int out_size, void* d_ws, size_t ws_size,
                              hipStream_t stream) {
  const float* feat  = (const float*)d_in[0];
  const float* dinit = (const float*)d_in[1];
  const float* enc   = (const float*)d_in[2];
  const float* W1    = (const float*)d_in[3];
  const float* b1    = (const float*)d_in[4];
  const float* W2    = (const float*)d_in[5];
  const float* b2    = (const float*)d_in[6];
  const float* W3    = (const float*)d_in[7];
  const float* W4    = (const float*)d_in[8];
  const float* b4    = (const float*)d_in[9];
  const float* W5    = (const float*)d_in[10];
  const float* b5    = (const float*)d_in[11];
  const float* W6    = (const float*)d_in[12];
  const float* b6    = (const float*)d_in[13];

  float*     out   = (float*)d_out;
  _Float16*  skbuf = (_Float16*)d_ws;   // 49152*384*2 = 37.7 MB workspace

  dec_phase1<<<dim3(64), dim3(512), 0, stream>>>(
      feat, dinit, enc, W1, b1, W2, b2, W3, W4, b4, skbuf, TPRED);
  dec_phase2<<<dim3(512), dim3(512), 0, stream>>>(
      skbuf, W5, b5, W6, b6, out);
}

// Round 9
// 152.562 us; speedup vs baseline: 2.1013x; 2.1013x over previous
//
#include <hip/hip_runtime.h>
#include <hip/hip_bf16.h>
#include <cstddef>

#define NB 2048
#define TENC 168
#define TPRED 24

typedef _Float16 h8 __attribute__((ext_vector_type(8)));
typedef float f4v __attribute__((ext_vector_type(4)));

#define MFMA16(a, b, c) __builtin_amdgcn_mfma_f32_16x16x32_f16((a), (b), (c), 0, 0, 0)

// LDS-only barrier: waits DS ops, does NOT drain vmcnt (global loads/stores
// stay in flight across it).
#define LBAR() asm volatile("s_waitcnt lgkmcnt(0)\ns_barrier" ::: "memory")

__device__ __forceinline__ float gate_fast(float a, float g) {
  a = fminf(a, 15.0f);
  const float e2a = __builtin_amdgcn_exp2f(a * 2.88539008177793f);    // e^(2a)
  const float eg  = __builtin_amdgcn_exp2f(g * -1.44269504088896f);   // e^(-g)
  return (e2a - 1.0f) * __builtin_amdgcn_rcpf((e2a + 1.0f) * (1.0f + eg));
}
__device__ __forceinline__ float tanh_fast(float u) {
  const float e2 = __builtin_amdgcn_exp2f(fminf(u, 15.0f) * 2.88539008177793f);
  return (e2 - 1.0f) * __builtin_amdgcn_rcpf(e2 + 1.0f);
}

// ---------------------------------------------------------------------------
// Phase 1 (round 9): r6 structure, 6 barrier-phases per step (T folded away).
// 128 blocks x 512 threads; block owns 16 elements (MFMA M=16).
// Producers (waves 0-3): recurrence. Z = x@W3 carried as f32 acc;
//   per layer: Z += gated@W43 ; S = state@W2+b2 (separate acc, depth-2 chain);
//   dc = Z+S -> gate -> g16v[l&1]. All states prefetched at phase 0.
// Consumers (waves 4-7): lagged out-GEMM lp=l-1 at phases 1..5; lp=5 of step
//   t-1 at phase 0 (idle slot); feat prefetch at phase 3; embed(t+1) at
//   phase 5 (xf16/xf32 parity-dbuf'd). Epilogue does lp=5 of the final step.
// setprio(1) on producers (role-split scheduling, T5).
// k-mapping k = kk*32 + q*8 + j consistent for all A/B frags.
// C/D layout: col = lane&15, row = (lane>>4)*4 + reg (verified m89).
// ---------------------------------------------------------------------------
__global__ __launch_bounds__(512, 1) void dec_phase1(
    const float* __restrict__ feat,    // [2048][24][15]
    const float* __restrict__ dinit,   // [2048][1]
    const float* __restrict__ enc,     // [6][2048][168][64]
    const float* __restrict__ W1,      // [16][64]
    const float* __restrict__ b1,      // [64]
    const float* __restrict__ W2,      // [64][128]
    const float* __restrict__ b2,      // [128]
    const float* __restrict__ W3,      // [64][128]
    const float* __restrict__ W4,      // [64][128]
    const float* __restrict__ b4,      // [128]
    _Float16* __restrict__ skbuf,      // [2048*24][384] f16
    int t_steps)                       // runtime 24: blocks t-loop unroll
{
  __shared__ _Float16 ring[23][16][72];  // 52.9 KB dilation rings / enc tails
  __shared__ _Float16 g16v[2][16][72];   //  4.5 KB gated, layer-parity dbuf
  __shared__ _Float16 xf16[2][16][72];   //  4.5 KB embed x(t), step-parity
  __shared__ float    xf32[2][64][20];   // 10.0 KB embed x(t) [col][el], parity
  __shared__ _Float16 W43h[64][136];     // 17.0 KB W4res@W3 (f16)

  const int tid = threadIdx.x;
  const int w   = tid >> 6;
  const int ln  = tid & 63;
  const int i   = ln & 15;
  const int q   = ln >> 4;
  const int q8  = q * 8;
  const int e0  = blockIdx.x * 16;

  // -------- prologue: W43 = W4[:,64:128] @ W3 (stage f32 in ring region) ---
  float* W3s  = (float*)&ring[0][0][0];   // [64][128] 32 KB
  float* W4rs = W3s + 64 * 128;           // [64][64]  16 KB (total 48 <= 52.9)
  for (int idx = tid; idx < 2048; idx += 512)
    ((float4*)W3s)[idx] = ((const float4*)W3)[idx];
  for (int idx = tid; idx < 1024; idx += 512) {
    const int row = idx >> 4, seg = idx & 15;
    *(float4*)&W4rs[row * 64 + seg * 4] = *(const float4*)&W4[row * 128 + 64 + seg * 4];
  }
  __syncthreads();
  {
    const int c = tid & 127, k0 = (tid >> 7) << 4;
    float acc[16];
    #pragma unroll
    for (int r = 0; r < 16; ++r) acc[r] = 0.0f;
    for (int m = 0; m < 64; ++m) {
      const float w3v = W3s[m * 128 + c];
      #pragma unroll
      for (int r = 0; r < 16; ++r) acc[r] += W4rs[(k0 + r) * 64 + m] * w3v;
    }
    #pragma unroll
    for (int r = 0; r < 16; ++r) W43h[k0 + r][c] = (_Float16)acc[r];
  }
  __syncthreads();   // W3s/W4rs dead; ring region reusable

  // -------- per-wave roles & weight fragments --------
  const int fs = w & 3;
  const int cf = 16 * fs + i;          // waves 0-3: f column (also consumer col)
  const int cg = 64 + cf;              // paired g column
  const int cw = w - 4;                // consumer wave id (w>=4)
  const int cs = 16 * cw + i;          // waves 4-7: skip col == res col == x col

  h8 BW2f[2], BW2g[2], BW3f[2], BW3g[2], B43f[2], B43g[2], B4s[2], B4r[2];
  float b2f = 0.f, b2g = 0.f, b4s_b = 0.f, b4r_b = 0.f;
  float w1r[16]; float b1r = 0.f; float ini4[4] = {0.f, 0.f, 0.f, 0.f};
  if (w < 4) {
    #pragma unroll
    for (int kk = 0; kk < 2; ++kk)
      #pragma unroll
      for (int j = 0; j < 8; ++j) {
        const int k = kk * 32 + q8 + j;
        BW2f[kk][j] = (_Float16)W2[k * 128 + cf];
        BW2g[kk][j] = (_Float16)W2[k * 128 + cg];
        BW3f[kk][j] = (_Float16)W3[k * 128 + cf];
        BW3g[kk][j] = (_Float16)W3[k * 128 + cg];
        B43f[kk][j] = W43h[k][cf];
        B43g[kk][j] = W43h[k][cg];
      }
    b2f = b2[cf]; b2g = b2[cg];
  } else {
    #pragma unroll
    for (int kk = 0; kk < 2; ++kk)
      #pragma unroll
      for (int j = 0; j < 8; ++j) {
        const int k = kk * 32 + q8 + j;
        B4s[kk][j] = (_Float16)W4[k * 128 + cs];
        B4r[kk][j] = (_Float16)W4[k * 128 + 64 + cs];
      }
    b4s_b = b4[cs]; b4r_b = b4[64 + cs];
    #pragma unroll
    for (int ii = 0; ii < 16; ++ii) w1r[ii] = W1[ii * 64 + ln];
    b1r = b1[ln];
    #pragma unroll
    for (int s2 = 0; s2 < 4; ++s2) ini4[s2] = dinit[e0 + 4 * cw + s2];
  }

  // -------- ring preload (l<=3 encoder tails) --------
  for (int idx = tid; idx < 1920; idx += 512) {
    const int c = idx & 7, el = (idx >> 3) & 15, s = idx >> 7;
    int l, j;
    if (s == 0)      { l = 0; j = 0; }
    else if (s < 3)  { l = 1; j = s - 1; }
    else if (s < 7)  { l = 2; j = s - 3; }
    else             { l = 3; j = s - 7; }
    const int d = 1 << l;
    const float* ep = enc + (((size_t)l * NB + e0 + el) * TENC + (TENC + j - d)) * 64 + c * 8;
    h8 hv;
    #pragma unroll
    for (int u = 0; u < 8; ++u) hv[u] = (_Float16)ep[u];
    *(h8*)&ring[s][el][c * 8] = hv;
  }

  // -------- t=0 embed (all waves, 2 els each, local temps) --------
  {
    float w1e[16];
    #pragma unroll
    for (int ii = 0; ii < 16; ++ii) w1e[ii] = W1[ii * 64 + ln];
    const float b1e = b1[ln];
    #pragma unroll
    for (int s = 0; s < 2; ++s) {
      const int el = 2 * w + s;
      const float* fp = feat + (size_t)(e0 + el) * TPRED * 15;
      float u = b1e + dinit[e0 + el] * w1e[0];
      #pragma unroll
      for (int ii = 0; ii < 15; ++ii) u += fp[ii] * w1e[ii + 1];
      const float xv = tanh_fast(u);
      xf16[0][el][ln] = (_Float16)xv;
      xf32[0][ln][el] = xv;
    }
  }
  __syncthreads();
  if (w < 4) __builtin_amdgcn_s_setprio(1);   // producers favored (T5)

  f4v Zf = {0,0,0,0}, Zg = {0,0,0,0};

  for (int t = 0; t < t_steps; ++t) {
    h8 s0a[4], s1a[4], s4a0, s4a1;           // producer: prefetched states
    f4v p4[4], p5[4];                         // producer: enc f32 slices
    f4v ff0[4], ff1[4], ff2[4];               // consumer: feat prefetch
    float2 ffd[4]; float ffe[4];
    f4v xreg = {0,0,0,0};                     // consumer running x

    for (int l = 0; l < 6; ++l) {
      if (w < 4) {
        // ================= PRODUCER =================
        if (l == 0) {
          // enc slices for l=4 (t<16) and l=5
          const int t4 = (t < 16) ? t : 0;
          const float* e4 = enc + (((size_t)4 * NB + e0 + i) * TENC + (152 + t4)) * 64 + q8;
          const float* e5 = enc + (((size_t)5 * NB + e0 + i) * TENC + (136 + t )) * 64 + q8;
          p4[0] = *(const f4v*)(e4);      p4[1] = *(const f4v*)(e4 + 4);
          p4[2] = *(const f4v*)(e4 + 32); p4[3] = *(const f4v*)(e4 + 36);
          p5[0] = *(const f4v*)(e5);      p5[1] = *(const f4v*)(e5 + 4);
          p5[2] = *(const f4v*)(e5 + 32); p5[3] = *(const f4v*)(e5 + 36);

          // ring-state prefetch, all layers
          #pragma unroll
          for (int ll = 0; ll < 4; ++ll) {
            const int d = 1 << ll;
            const int slot = (d - 1) + (t & (d - 1));
            s0a[ll] = *(const h8*)&ring[slot][i][q8];
            s1a[ll] = *(const h8*)&ring[slot][i][32 + q8];
          }
          {
            const int slot4 = 15 + (t & 7);
            s4a0 = *(const h8*)&ring[slot4][i][q8];      // garbage if t<16 (unused)
            s4a1 = *(const h8*)&ring[slot4][i][32 + q8];
          }

          // Z_0 = x_0 @ W3
          const h8 a2 = *(const h8*)&xf16[t & 1][i][q8];
          const h8 a3 = *(const h8*)&xf16[t & 1][i][32 + q8];
          Zf = (f4v){0,0,0,0};  Zg = (f4v){0,0,0,0};
          Zf = MFMA16(a2, BW3f[0], Zf); Zf = MFMA16(a3, BW3f[1], Zf);
          Zg = MFMA16(a2, BW3g[0], Zg); Zg = MFMA16(a3, BW3g[1], Zg);

          // S_0 (separate acc, depth-2) ; dc_0 = Z_0 + S_0
          f4v Sf = {b2f, b2f, b2f, b2f}, Sg = {b2g, b2g, b2g, b2g};
          Sf = MFMA16(s0a[0], BW2f[0], Sf); Sf = MFMA16(s1a[0], BW2f[1], Sf);
          Sg = MFMA16(s0a[0], BW2g[0], Sg); Sg = MFMA16(s1a[0], BW2g[1], Sg);
          #pragma unroll
          for (int r = 0; r < 4; ++r) {
            const float gd = gate_fast(Zf[r] + Sf[r], Zg[r] + Sg[r]);
            g16v[0][4 * q + r][cf] = (_Float16)gd;
          }
        } else {
          const h8 gA0 = *(const h8*)&g16v[(l - 1) & 1][i][q8];
          const h8 gA1 = *(const h8*)&g16v[(l - 1) & 1][i][32 + q8];
          Zf = MFMA16(gA0, B43f[0], Zf); Zf = MFMA16(gA1, B43f[1], Zf);
          Zg = MFMA16(gA0, B43g[0], Zg); Zg = MFMA16(gA1, B43g[1], Zg);
          h8 sa0, sa1;
          if (l <= 3) { sa0 = s0a[l]; sa1 = s1a[l]; }
          else if (l == 4) {
            if (t < 16) {
              #pragma unroll
              for (int u = 0; u < 4; ++u) {
                sa0[u] = (_Float16)p4[0][u]; sa0[u + 4] = (_Float16)p4[1][u];
                sa1[u] = (_Float16)p4[2][u]; sa1[u + 4] = (_Float16)p4[3][u];
              }
            } else { sa0 = s4a0; sa1 = s4a1; }
          } else {
            #pragma unroll
            for (int u = 0; u < 4; ++u) {
              sa0[u] = (_Float16)p5[0][u]; sa0[u + 4] = (_Float16)p5[1][u];
              sa1[u] = (_Float16)p5[2][u]; sa1[u + 4] = (_Float16)p5[3][u];
            }
          }
          f4v Sf = {b2f, b2f, b2f, b2f}, Sg = {b2g, b2g, b2g, b2g};
          Sf = MFMA16(sa0, BW2f[0], Sf); Sf = MFMA16(sa1, BW2f[1], Sf);
          Sg = MFMA16(sa0, BW2g[0], Sg); Sg = MFMA16(sa1, BW2g[1], Sg);
          #pragma unroll
          for (int r = 0; r < 4; ++r) {
            const float gd = gate_fast(Zf[r] + Sf[r], Zg[r] + Sg[r]);
            g16v[l & 1][4 * q + r][cf] = (_Float16)gd;
          }
        }
      } else {
        // ================= CONSUMER =================
        if (l == 0) {
          xreg = *(const f4v*)&xf32[t & 1][cs][4 * q];   // x_0(t)
          if (t > 0) {
            // lagged lp=5 skip of step t-1 (g16v[1] untouched since then)
            const h8 g0 = *(const h8*)&g16v[1][i][q8];
            const h8 g1 = *(const h8*)&g16v[1][i][32 + q8];
            f4v osk = {b4s_b, b4s_b, b4s_b, b4s_b};
            osk = MFMA16(g0, B4s[0], osk); osk = MFMA16(g1, B4s[1], osk);
            #pragma unroll
            for (int r = 0; r < 4; ++r)
              skbuf[((size_t)(e0 + 4 * q + r) * TPRED + (t - 1)) * 384 + 5 * 64 + cs] =
                  (_Float16)fmaxf(osk[r], 0.0f);
          }
        } else {
          const int lp  = l - 1;
          const int dlp = 1 << lp;
          const int slotlp = (lp <= 3) ? (dlp - 1) + (t & (dlp - 1)) : 15 + (t & 7);
          const h8 g0 = *(const h8*)&g16v[(l - 1) & 1][i][q8];
          const h8 g1 = *(const h8*)&g16v[(l - 1) & 1][i][32 + q8];
          f4v osk = {b4s_b, b4s_b, b4s_b, b4s_b};
          osk = MFMA16(g0, B4s[0], osk); osk = MFMA16(g1, B4s[1], osk);
          f4v ore = {b4r_b, b4r_b, b4r_b, b4r_b};
          ore = MFMA16(g0, B4r[0], ore); ore = MFMA16(g1, B4r[1], ore);
          const bool wr = (t + dlp) <= 23;
          #pragma unroll
          for (int r = 0; r < 4; ++r) {
            skbuf[((size_t)(e0 + 4 * q + r) * TPRED + t) * 384 + lp * 64 + cs] =
                (_Float16)fmaxf(osk[r], 0.0f);
            const float xn = xreg[r] + ore[r];
            xreg[r] = xn;
            if (wr) ring[slotlp][4 * q + r][cs] = (_Float16)xn;
          }
        }
        if (l == 3 && t + 1 < t_steps) {
          // feat prefetch for embed(t+1)
          #pragma unroll
          for (int s2 = 0; s2 < 4; ++s2) {
            const float* fp = feat + ((size_t)(e0 + 4 * cw + s2) * TPRED + (t + 1)) * 15;
            ff0[s2] = *(const f4v*)(fp);
            ff1[s2] = *(const f4v*)(fp + 4);
            ff2[s2] = *(const f4v*)(fp + 8);
            ffd[s2] = *(const float2*)(fp + 12);
            ffe[s2] = fp[14];
          }
        }
        if (l == 5 && t + 1 < t_steps) {
          // embed(t+1) -> parity (t+1)&1
          #pragma unroll
          for (int s2 = 0; s2 < 4; ++s2) {
            const int el = 4 * cw + s2;
            float u = b1r + ini4[s2] * w1r[0];
            u += ff0[s2][0] * w1r[1]  + ff0[s2][1] * w1r[2]  + ff0[s2][2] * w1r[3]  + ff0[s2][3] * w1r[4];
            u += ff1[s2][0] * w1r[5]  + ff1[s2][1] * w1r[6]  + ff1[s2][2] * w1r[7]  + ff1[s2][3] * w1r[8];
            u += ff2[s2][0] * w1r[9]  + ff2[s2][1] * w1r[10] + ff2[s2][2] * w1r[11] + ff2[s2][3] * w1r[12];
            u += ffd[s2].x  * w1r[13] + ffd[s2].y  * w1r[14] + ffe[s2]    * w1r[15];
            const float xv = tanh_fast(u);
            xf16[(t + 1) & 1][el][ln] = (_Float16)xv;
            xf32[(t + 1) & 1][ln][el] = xv;
          }
        }
      }
      LBAR();
    }
  }

  // -------- epilogue: lp=5 skip of the final step --------
  if (w >= 4) {
    const int s = t_steps - 1;
    const h8 g0 = *(const h8*)&g16v[1][i][q8];
    const h8 g1 = *(const h8*)&g16v[1][i][32 + q8];
    f4v osk = {b4s_b, b4s_b, b4s_b, b4s_b};
    osk = MFMA16(g0, B4s[0], osk); osk = MFMA16(g1, B4s[1], osk);
    #pragma unroll
    for (int r = 0; r < 4; ++r)
      skbuf[((size_t)(e0 + 4 * q + r) * TPRED + s) * 384 + 5 * 64 + cs] =
          (_Float16)fmaxf(osk[r], 0.0f);
  }
}

// ---------------------------------------------------------------------------
// Phase 2: y = relu( sk @ W5 + b5 ) @ W6 + b6, 49152 rows, f16 MFMA.
// 512 blocks x 96 rows; 76.5 KB LDS -> 2 blocks/CU.
// ---------------------------------------------------------------------------
__global__ __launch_bounds__(512, 1) void dec_phase2(
    const _Float16* __restrict__ skbuf,  // [49152][384] f16 (already relu'd)
    const float* __restrict__ W5,        // [384][128]
    const float* __restrict__ b5,        // [128]
    const float* __restrict__ W6,        // [128]
    const float* __restrict__ b6,        // [1]
    float* __restrict__ out)             // [49152]
{
  __shared__ _Float16 As[96][392];       // 73.5 KB
  __shared__ float red[96][8];           // 3 KB

  const int tid = threadIdx.x;
  const int w   = tid >> 6;
  const int ln  = tid & 63;
  const int i   = ln & 15;
  const int q   = ln >> 4;
  const int R0  = blockIdx.x * 96;
  const int col = 16 * w + i;

  h8 B5[12];
  #pragma unroll
  for (int kk = 0; kk < 12; ++kk)
    #pragma unroll
    for (int j = 0; j < 8; ++j)
      B5[kk][j] = (_Float16)W5[(size_t)(kk * 32 + q * 8 + j) * 128 + col];
  const float b5r = b5[col], w6r = W6[col];

  #pragma unroll
  for (int it = 0; it < 9; ++it) {
    const int idx = tid + it * 512;            // 0..4607 = 96 rows x 48 segs
    const h8 v = *(const h8*)&skbuf[(size_t)(R0 + idx / 48) * 384 + (idx % 48) * 8];
    *(h8*)&As[idx / 48][(idx % 48) * 8] = v;
  }
  __syncthreads();

  #pragma unroll
  for (int m = 0; m < 6; ++m) {
    f4v acc = {0, 0, 0, 0};
    #pragma unroll
    for (int kk = 0; kk < 12; ++kk) {
      const h8 a = *(const h8*)&As[16 * m + i][kk * 32 + q * 8];
      acc = MFMA16(a, B5[kk], acc);
    }
    float py[4];
    #pragma unroll
    for (int r = 0; r < 4; ++r)
      py[r] = fmaxf(acc[r] + b5r, 0.0f) * w6r;
    #pragma unroll
    for (int r = 0; r < 4; ++r) {
      float v = py[r];
      v += __shfl_xor(v, 1);
      v += __shfl_xor(v, 2);
      v += __shfl_xor(v, 4);
      v += __shfl_xor(v, 8);
      py[r] = v;
    }
    if (i == 0) {
      #pragma unroll
      for (int r = 0; r < 4; ++r) red[16 * m + 4 * q + r][w] = py[r];
    }
  }
  __syncthreads();

  if (tid < 96) {
    const f4v r0 = *(const f4v*)&red[tid][0];
    const f4v r1 = *(const f4v*)&red[tid][4];
    out[R0 + tid] = b6[0] + r0[0] + r0[1] + r0[2] + r0[3]
                          + r1[0] + r1[1] + r1[2] + r1[3];
  }
}

extern "C" void kernel_launch(void* const* d_in, const int* in_sizes, int n_in,
                              void* d_out, int out_size, void* d_ws, size_t ws_size,
                              hipStream_t stream) {
  const float* feat  = (const float*)d_in[0];
  const float* dinit = (const float*)d_in[1];
  const float* enc   = (const float*)d_in[2];
  const float* W1    = (const float*)d_in[3];
  const float* b1    = (const float*)d_in[4];
  const float* W2    = (const float*)d_in[5];
  const float* b2    = (const float*)d_in[6];
  const float* W3    = (const float*)d_in[7];
  const float* W4    = (const float*)d_in[8];
  const float* b4    = (const float*)d_in[9];
  const float* W5    = (const float*)d_in[10];
  const float* b5    = (const float*)d_in[11];
  const float* W6    = (const float*)d_in[12];
  const float* b6    = (const float*)d_in[13];

  float*     out   = (float*)d_out;
  _Float16*  skbuf = (_Float16*)d_ws;   // 49152*384*2 = 37.7 MB workspace

  dec_phase1<<<dim3(128), dim3(512), 0, stream>>>(
      feat, dinit, enc, W1, b1, W2, b2, W3, W4, b4, skbuf, TPRED);
  dec_phase2<<<dim3(512), dim3(512), 0, stream>>>(
      skbuf, W5, b5, W6, b6, out);
}

// Round 10
// 152.257 us; speedup vs baseline: 2.1056x; 1.0020x over previous
//
#include <hip/hip_runtime.h>
#include <hip/hip_bf16.h>
#include <cstddef>

#define NB 2048
#define TENC 168
#define TPRED 24

typedef _Float16 h8 __attribute__((ext_vector_type(8)));
typedef float f4v __attribute__((ext_vector_type(4)));

#define MFMA16(a, b, c) __builtin_amdgcn_mfma_f32_16x16x32_f16((a), (b), (c), 0, 0, 0)

// LDS-only barrier: waits DS ops, does NOT drain vmcnt (global loads/stores
// stay in flight across it).
#define LBAR() asm volatile("s_waitcnt lgkmcnt(0)\ns_barrier" ::: "memory")

__device__ __forceinline__ float gate_fast(float a, float g) {
  a = fminf(a, 15.0f);
  const float e2a = __builtin_amdgcn_exp2f(a * 2.88539008177793f);    // e^(2a)
  const float eg  = __builtin_amdgcn_exp2f(g * -1.44269504088896f);   // e^(-g)
  return (e2a - 1.0f) * __builtin_amdgcn_rcpf((e2a + 1.0f) * (1.0f + eg));
}
__device__ __forceinline__ float tanh_fast(float u) {
  const float e2 = __builtin_amdgcn_exp2f(fminf(u, 15.0f) * 2.88539008177793f);
  return (e2 - 1.0f) * __builtin_amdgcn_rcpf(e2 + 1.0f);
}

// ---------------------------------------------------------------------------
// Phase 1 (round 9): r6 structure, 6 barrier-phases per step (T folded away).
// 128 blocks x 512 threads; block owns 16 elements (MFMA M=16).
// Producers (waves 0-3): recurrence. Z = x@W3 carried as f32 acc;
//   per layer: Z += gated@W43 ; S = state@W2+b2 (separate acc, depth-2 chain);
//   dc = Z+S -> gate -> g16v[l&1]. All states prefetched at phase 0.
// Consumers (waves 4-7): lagged out-GEMM lp=l-1 at phases 1..5; lp=5 of step
//   t-1 at phase 0 (idle slot); feat prefetch at phase 3; embed(t+1) at
//   phase 5 (xf16/xf32 parity-dbuf'd). Epilogue does lp=5 of the final step.
// setprio(1) on producers (role-split scheduling, T5).
// k-mapping k = kk*32 + q*8 + j consistent for all A/B frags.
// C/D layout: col = lane&15, row = (lane>>4)*4 + reg (verified m89).
// ---------------------------------------------------------------------------
__global__ __launch_bounds__(512, 1) void dec_phase1(
    const float* __restrict__ feat,    // [2048][24][15]
    const float* __restrict__ dinit,   // [2048][1]
    const float* __restrict__ enc,     // [6][2048][168][64]
    const float* __restrict__ W1,      // [16][64]
    const float* __restrict__ b1,      // [64]
    const float* __restrict__ W2,      // [64][128]
    const float* __restrict__ b2,      // [128]
    const float* __restrict__ W3,      // [64][128]
    const float* __restrict__ W4,      // [64][128]
    const float* __restrict__ b4,      // [128]
    _Float16* __restrict__ skbuf,      // [2048*24][384] f16
    int t_steps)                       // runtime 24: blocks t-loop unroll
{
  __shared__ _Float16 ring[23][16][72];  // 52.9 KB dilation rings / enc tails
  __shared__ _Float16 g16v[2][16][72];   //  4.5 KB gated, layer-parity dbuf
  __shared__ _Float16 xf16[2][16][72];   //  4.5 KB embed x(t), step-parity
  __shared__ float    xf32[2][64][20];   // 10.0 KB embed x(t) [col][el], parity
  __shared__ _Float16 W43h[64][136];     // 17.0 KB W4res@W3 (f16)

  const int tid = threadIdx.x;
  const int w   = tid >> 6;
  const int ln  = tid & 63;
  const int i   = ln & 15;
  const int q   = ln >> 4;
  const int q8  = q * 8;
  const int e0  = blockIdx.x * 16;

  // -------- prologue: W43 = W4[:,64:128] @ W3 (stage f32 in ring region) ---
  float* W3s  = (float*)&ring[0][0][0];   // [64][128] 32 KB
  float* W4rs = W3s + 64 * 128;           // [64][64]  16 KB (total 48 <= 52.9)
  for (int idx = tid; idx < 2048; idx += 512)
    ((float4*)W3s)[idx] = ((const float4*)W3)[idx];
  for (int idx = tid; idx < 1024; idx += 512) {
    const int row = idx >> 4, seg = idx & 15;
    *(float4*)&W4rs[row * 64 + seg * 4] = *(const float4*)&W4[row * 128 + 64 + seg * 4];
  }
  __syncthreads();
  {
    const int c = tid & 127, k0 = (tid >> 7) << 4;
    float acc[16];
    #pragma unroll
    for (int r = 0; r < 16; ++r) acc[r] = 0.0f;
    for (int m = 0; m < 64; ++m) {
      const float w3v = W3s[m * 128 + c];
      #pragma unroll
      for (int r = 0; r < 16; ++r) acc[r] += W4rs[(k0 + r) * 64 + m] * w3v;
    }
    #pragma unroll
    for (int r = 0; r < 16; ++r) W43h[k0 + r][c] = (_Float16)acc[r];
  }
  __syncthreads();   // W3s/W4rs dead; ring region reusable

  // -------- per-wave roles & weight fragments --------
  const int fs = w & 3;
  const int cf = 16 * fs + i;          // waves 0-3: f column (also consumer col)
  const int cg = 64 + cf;              // paired g column
  const int cw = w - 4;                // consumer wave id (w>=4)
  const int cs = 16 * cw + i;          // waves 4-7: skip col == res col == x col

  h8 BW2f[2], BW2g[2], BW3f[2], BW3g[2], B43f[2], B43g[2], B4s[2], B4r[2];
  float b2f = 0.f, b2g = 0.f, b4s_b = 0.f, b4r_b = 0.f;
  float w1r[16]; float b1r = 0.f; float ini4[4] = {0.f, 0.f, 0.f, 0.f};
  if (w < 4) {
    #pragma unroll
    for (int kk = 0; kk < 2; ++kk)
      #pragma unroll
      for (int j = 0; j < 8; ++j) {
        const int k = kk * 32 + q8 + j;
        BW2f[kk][j] = (_Float16)W2[k * 128 + cf];
        BW2g[kk][j] = (_Float16)W2[k * 128 + cg];
        BW3f[kk][j] = (_Float16)W3[k * 128 + cf];
        BW3g[kk][j] = (_Float16)W3[k * 128 + cg];
        B43f[kk][j] = W43h[k][cf];
        B43g[kk][j] = W43h[k][cg];
      }
    b2f = b2[cf]; b2g = b2[cg];
  } else {
    #pragma unroll
    for (int kk = 0; kk < 2; ++kk)
      #pragma unroll
      for (int j = 0; j < 8; ++j) {
        const int k = kk * 32 + q8 + j;
        B4s[kk][j] = (_Float16)W4[k * 128 + cs];
        B4r[kk][j] = (_Float16)W4[k * 128 + 64 + cs];
      }
    b4s_b = b4[cs]; b4r_b = b4[64 + cs];
    #pragma unroll
    for (int ii = 0; ii < 16; ++ii) w1r[ii] = W1[ii * 64 + ln];
    b1r = b1[ln];
    #pragma unroll
    for (int s2 = 0; s2 < 4; ++s2) ini4[s2] = dinit[e0 + 4 * cw + s2];
  }

  // -------- ring preload (l<=3 encoder tails) --------
  for (int idx = tid; idx < 1920; idx += 512) {
    const int c = idx & 7, el = (idx >> 3) & 15, s = idx >> 7;
    int l, j;
    if (s == 0)      { l = 0; j = 0; }
    else if (s < 3)  { l = 1; j = s - 1; }
    else if (s < 7)  { l = 2; j = s - 3; }
    else             { l = 3; j = s - 7; }
    const int d = 1 << l;
    const float* ep = enc + (((size_t)l * NB + e0 + el) * TENC + (TENC + j - d)) * 64 + c * 8;
    h8 hv;
    #pragma unroll
    for (int u = 0; u < 8; ++u) hv[u] = (_Float16)ep[u];
    *(h8*)&ring[s][el][c * 8] = hv;
  }

  // -------- t=0 embed (all waves, 2 els each, local temps) --------
  {
    float w1e[16];
    #pragma unroll
    for (int ii = 0; ii < 16; ++ii) w1e[ii] = W1[ii * 64 + ln];
    const float b1e = b1[ln];
    #pragma unroll
    for (int s = 0; s < 2; ++s) {
      const int el = 2 * w + s;
      const float* fp = feat + (size_t)(e0 + el) * TPRED * 15;
      float u = b1e + dinit[e0 + el] * w1e[0];
      #pragma unroll
      for (int ii = 0; ii < 15; ++ii) u += fp[ii] * w1e[ii + 1];
      const float xv = tanh_fast(u);
      xf16[0][el][ln] = (_Float16)xv;
      xf32[0][ln][el] = xv;
    }
  }
  __syncthreads();
  if (w < 4) __builtin_amdgcn_s_setprio(1);   // producers favored (T5)

  f4v Zf = {0,0,0,0}, Zg = {0,0,0,0};

  for (int t = 0; t < t_steps; ++t) {
    h8 s0a[4], s1a[4], s4a0, s4a1;           // producer: prefetched states
    f4v p4[4], p5[4];                         // producer: enc f32 slices
    f4v ff0[4], ff1[4], ff2[4];               // consumer: feat prefetch
    float2 ffd[4]; float ffe[4];
    f4v xreg = {0,0,0,0};                     // consumer running x

    for (int l = 0; l < 6; ++l) {
      if (w < 4) {
        // ================= PRODUCER =================
        if (l == 0) {
          // enc slices for l=4 (t<16) and l=5
          const int t4 = (t < 16) ? t : 0;
          const float* e4 = enc + (((size_t)4 * NB + e0 + i) * TENC + (152 + t4)) * 64 + q8;
          const float* e5 = enc + (((size_t)5 * NB + e0 + i) * TENC + (136 + t )) * 64 + q8;
          p4[0] = *(const f4v*)(e4);      p4[1] = *(const f4v*)(e4 + 4);
          p4[2] = *(const f4v*)(e4 + 32); p4[3] = *(const f4v*)(e4 + 36);
          p5[0] = *(const f4v*)(e5);      p5[1] = *(const f4v*)(e5 + 4);
          p5[2] = *(const f4v*)(e5 + 32); p5[3] = *(const f4v*)(e5 + 36);

          // ring-state prefetch, all layers
          #pragma unroll
          for (int ll = 0; ll < 4; ++ll) {
            const int d = 1 << ll;
            const int slot = (d - 1) + (t & (d - 1));
            s0a[ll] = *(const h8*)&ring[slot][i][q8];
            s1a[ll] = *(const h8*)&ring[slot][i][32 + q8];
          }
          {
            const int slot4 = 15 + (t & 7);
            s4a0 = *(const h8*)&ring[slot4][i][q8];      // garbage if t<16 (unused)
            s4a1 = *(const h8*)&ring[slot4][i][32 + q8];
          }

          // Z_0 = x_0 @ W3
          const h8 a2 = *(const h8*)&xf16[t & 1][i][q8];
          const h8 a3 = *(const h8*)&xf16[t & 1][i][32 + q8];
          Zf = (f4v){0,0,0,0};  Zg = (f4v){0,0,0,0};
          Zf = MFMA16(a2, BW3f[0], Zf); Zf = MFMA16(a3, BW3f[1], Zf);
          Zg = MFMA16(a2, BW3g[0], Zg); Zg = MFMA16(a3, BW3g[1], Zg);

          // S_0 (separate acc, depth-2) ; dc_0 = Z_0 + S_0
          f4v Sf = {b2f, b2f, b2f, b2f}, Sg = {b2g, b2g, b2g, b2g};
          Sf = MFMA16(s0a[0], BW2f[0], Sf); Sf = MFMA16(s1a[0], BW2f[1], Sf);
          Sg = MFMA16(s0a[0], BW2g[0], Sg); Sg = MFMA16(s1a[0], BW2g[1], Sg);
          #pragma unroll
          for (int r = 0; r < 4; ++r) {
            const float gd = gate_fast(Zf[r] + Sf[r], Zg[r] + Sg[r]);
            g16v[0][4 * q + r][cf] = (_Float16)gd;
          }
        } else {
          const h8 gA0 = *(const h8*)&g16v[(l - 1) & 1][i][q8];
          const h8 gA1 = *(const h8*)&g16v[(l - 1) & 1][i][32 + q8];
          Zf = MFMA16(gA0, B43f[0], Zf); Zf = MFMA16(gA1, B43f[1], Zf);
          Zg = MFMA16(gA0, B43g[0], Zg); Zg = MFMA16(gA1, B43g[1], Zg);
          h8 sa0, sa1;
          if (l <= 3) { sa0 = s0a[l]; sa1 = s1a[l]; }
          else if (l == 4) {
            if (t < 16) {
              #pragma unroll
              for (int u = 0; u < 4; ++u) {
                sa0[u] = (_Float16)p4[0][u]; sa0[u + 4] = (_Float16)p4[1][u];
                sa1[u] = (_Float16)p4[2][u]; sa1[u + 4] = (_Float16)p4[3][u];
              }
            } else { sa0 = s4a0; sa1 = s4a1; }
          } else {
            #pragma unroll
            for (int u = 0; u < 4; ++u) {
              sa0[u] = (_Float16)p5[0][u]; sa0[u + 4] = (_Float16)p5[1][u];
              sa1[u] = (_Float16)p5[2][u]; sa1[u + 4] = (_Float16)p5[3][u];
            }
          }
          f4v Sf = {b2f, b2f, b2f, b2f}, Sg = {b2g, b2g, b2g, b2g};
          Sf = MFMA16(sa0, BW2f[0], Sf); Sf = MFMA16(sa1, BW2f[1], Sf);
          Sg = MFMA16(sa0, BW2g[0], Sg); Sg = MFMA16(sa1, BW2g[1], Sg);
          #pragma unroll
          for (int r = 0; r < 4; ++r) {
            const float gd = gate_fast(Zf[r] + Sf[r], Zg[r] + Sg[r]);
            g16v[l & 1][4 * q + r][cf] = (_Float16)gd;
          }
        }
      } else {
        // ================= CONSUMER =================
        if (l == 0) {
          xreg = *(const f4v*)&xf32[t & 1][cs][4 * q];   // x_0(t)
          if (t > 0) {
            // lagged lp=5 skip of step t-1 (g16v[1] untouched since then)
            const h8 g0 = *(const h8*)&g16v[1][i][q8];
            const h8 g1 = *(const h8*)&g16v[1][i][32 + q8];
            f4v osk = {b4s_b, b4s_b, b4s_b, b4s_b};
            osk = MFMA16(g0, B4s[0], osk); osk = MFMA16(g1, B4s[1], osk);
            #pragma unroll
            for (int r = 0; r < 4; ++r)
              skbuf[((size_t)(e0 + 4 * q + r) * TPRED + (t - 1)) * 384 + 5 * 64 + cs] =
                  (_Float16)fmaxf(osk[r], 0.0f);
          }
        } else {
          const int lp  = l - 1;
          const int dlp = 1 << lp;
          const int slotlp = (lp <= 3) ? (dlp - 1) + (t & (dlp - 1)) : 15 + (t & 7);
          const h8 g0 = *(const h8*)&g16v[(l - 1) & 1][i][q8];
          const h8 g1 = *(const h8*)&g16v[(l - 1) & 1][i][32 + q8];
          f4v osk = {b4s_b, b4s_b, b4s_b, b4s_b};
          osk = MFMA16(g0, B4s[0], osk); osk = MFMA16(g1, B4s[1], osk);
          f4v ore = {b4r_b, b4r_b, b4r_b, b4r_b};
          ore = MFMA16(g0, B4r[0], ore); ore = MFMA16(g1, B4r[1], ore);
          const bool wr = (t + dlp) <= 23;
          #pragma unroll
          for (int r = 0; r < 4; ++r) {
            skbuf[((size_t)(e0 + 4 * q + r) * TPRED + t) * 384 + lp * 64 + cs] =
                (_Float16)fmaxf(osk[r], 0.0f);
            const float xn = xreg[r] + ore[r];
            xreg[r] = xn;
            if (wr) ring[slotlp][4 * q + r][cs] = (_Float16)xn;
          }
        }
        if (l == 3 && t + 1 < t_steps) {
          // feat prefetch for embed(t+1)
          #pragma unroll
          for (int s2 = 0; s2 < 4; ++s2) {
            const float* fp = feat + ((size_t)(e0 + 4 * cw + s2) * TPRED + (t + 1)) * 15;
            ff0[s2] = *(const f4v*)(fp);
            ff1[s2] = *(const f4v*)(fp + 4);
            ff2[s2] = *(const f4v*)(fp + 8);
            ffd[s2] = *(const float2*)(fp + 12);
            ffe[s2] = fp[14];
          }
        }
        if (l == 5 && t + 1 < t_steps) {
          // embed(t+1) -> parity (t+1)&1
          #pragma unroll
          for (int s2 = 0; s2 < 4; ++s2) {
            const int el = 4 * cw + s2;
            float u = b1r + ini4[s2] * w1r[0];
            u += ff0[s2][0] * w1r[1]  + ff0[s2][1] * w1r[2]  + ff0[s2][2] * w1r[3]  + ff0[s2][3] * w1r[4];
            u += ff1[s2][0] * w1r[5]  + ff1[s2][1] * w1r[6]  + ff1[s2][2] * w1r[7]  + ff1[s2][3] * w1r[8];
            u += ff2[s2][0] * w1r[9]  + ff2[s2][1] * w1r[10] + ff2[s2][2] * w1r[11] + ff2[s2][3] * w1r[12];
            u += ffd[s2].x  * w1r[13] + ffd[s2].y  * w1r[14] + ffe[s2]    * w1r[15];
            const float xv = tanh_fast(u);
            xf16[(t + 1) & 1][el][ln] = (_Float16)xv;
            xf32[(t + 1) & 1][ln][el] = xv;
          }
        }
      }
      LBAR();
    }
  }

  // -------- epilogue: lp=5 skip of the final step --------
  if (w >= 4) {
    const int s = t_steps - 1;
    const h8 g0 = *(const h8*)&g16v[1][i][q8];
    const h8 g1 = *(const h8*)&g16v[1][i][32 + q8];
    f4v osk = {b4s_b, b4s_b, b4s_b, b4s_b};
    osk = MFMA16(g0, B4s[0], osk); osk = MFMA16(g1, B4s[1], osk);
    #pragma unroll
    for (int r = 0; r < 4; ++r)
      skbuf[((size_t)(e0 + 4 * q + r) * TPRED + s) * 384 + 5 * 64 + cs] =
          (_Float16)fmaxf(osk[r], 0.0f);
  }
}

// ---------------------------------------------------------------------------
// Phase 2: y = relu( sk @ W5 + b5 ) @ W6 + b6, 49152 rows, f16 MFMA.
// 512 blocks x 96 rows; 76.5 KB LDS -> 2 blocks/CU.
// ---------------------------------------------------------------------------
__global__ __launch_bounds__(512, 1) void dec_phase2(
    const _Float16* __restrict__ skbuf,  // [49152][384] f16 (already relu'd)
    const float* __restrict__ W5,        // [384][128]
    const float* __restrict__ b5,        // [128]
    const float* __restrict__ W6,        // [128]
    const float* __restrict__ b6,        // [1]
    float* __restrict__ out)             // [49152]
{
  __shared__ _Float16 As[96][392];       // 73.5 KB
  __shared__ float red[96][8];           // 3 KB

  const int tid = threadIdx.x;
  const int w   = tid >> 6;
  const int ln  = tid & 63;
  const int i   = ln & 15;
  const int q   = ln >> 4;
  const int R0  = blockIdx.x * 96;
  const int col = 16 * w + i;

  h8 B5[12];
  #pragma unroll
  for (int kk = 0; kk < 12; ++kk)
    #pragma unroll
    for (int j = 0; j < 8; ++j)
      B5[kk][j] = (_Float16)W5[(size_t)(kk * 32 + q * 8 + j) * 128 + col];
  const float b5r = b5[col], w6r = W6[col];

  #pragma unroll
  for (int it = 0; it < 9; ++it) {
    const int idx = tid + it * 512;            // 0..4607 = 96 rows x 48 segs
    const h8 v = *(const h8*)&skbuf[(size_t)(R0 + idx / 48) * 384 + (idx % 48) * 8];
    *(h8*)&As[idx / 48][(idx % 48) * 8] = v;
  }
  __syncthreads();

  #pragma unroll
  for (int m = 0; m < 6; ++m) {
    f4v acc = {0, 0, 0, 0};
    #pragma unroll
    for (int kk = 0; kk < 12; ++kk) {
      const h8 a = *(const h8*)&As[16 * m + i][kk * 32 + q * 8];
      acc = MFMA16(a, B5[kk], acc);
    }
    float py[4];
    #pragma unroll
    for (int r = 0; r < 4; ++r)
      py[r] = fmaxf(acc[r] + b5r, 0.0f) * w6r;
    #pragma unroll
    for (int r = 0; r < 4; ++r) {
      float v = py[r];
      v += __shfl_xor(v, 1);
      v += __shfl_xor(v, 2);
      v += __shfl_xor(v, 4);
      v += __shfl_xor(v, 8);
      py[r] = v;
    }
    if (i == 0) {
      #pragma unroll
      for (int r = 0; r < 4; ++r) red[16 * m + 4 * q + r][w] = py[r];
    }
  }
  __syncthreads();

  if (tid < 96) {
    const f4v r0 = *(const f4v*)&red[tid][0];
    const f4v r1 = *(const f4v*)&red[tid][4];
    out[R0 + tid] = b6[0] + r0[0] + r0[1] + r0[2] + r0[3]
                          + r1[0] + r1[1] + r1[2] + r1[3];
  }
}

extern "C" void kernel_launch(void* const* d_in, const int* in_sizes, int n_in,
                              void* d_out, int out_size, void* d_ws, size_t ws_size,
                              hipStream_t stream) {
  const float* feat  = (const float*)d_in[0];
  const float* dinit = (const float*)d_in[1];
  const float* enc   = (const float*)d_in[2];
  const float* W1    = (const float*)d_in[3];
  const float* b1    = (const float*)d_in[4];
  const float* W2    = (const float*)d_in[5];
  const float* b2    = (const float*)d_in[6];
  const float* W3    = (const float*)d_in[7];
  const float* W4    = (const float*)d_in[8];
  const float* b4    = (const float*)d_in[9];
  const float* W5    = (const float*)d_in[10];
  const float* b5    = (const float*)d_in[11];
  const float* W6    = (const float*)d_in[12];
  const float* b6    = (const float*)d_in[13];

  float*     out   = (float*)d_out;
  _Float16*  skbuf = (_Float16*)d_ws;   // 49152*384*2 = 37.7 MB workspace

  dec_phase1<<<dim3(128), dim3(512), 0, stream>>>(
      feat, dinit, enc, W1, b1, W2, b2, W3, W4, b4, skbuf, TPRED);
  dec_phase2<<<dim3(512), dim3(512), 0, stream>>>(
      skbuf, W5, b5, W6, b6, out);
}